// Round 1
// baseline (7665.288 us; speedup 1.0000x reference)
//
#include <hip/hip_runtime.h>
#include <stdint.h>

typedef unsigned short u16;
typedef __bf16 bf16x8 __attribute__((ext_vector_type(8)));
typedef float  f32x4  __attribute__((ext_vector_type(4)));

static __device__ __forceinline__ u16 f2bf(float x){
  uint32_t u = __float_as_uint(x);
  u += 0x7fffu + ((u >> 16) & 1u);   // RNE
  return (u16)(u >> 16);
}

// ---------------- f32 -> bf16 convert (vectorized, grid-stride) ----------------
__global__ __launch_bounds__(256) void conv_bf16_k(const float* __restrict__ src,
                                                   u16* __restrict__ dst, int n4){
  int i = blockIdx.x * 256 + threadIdx.x;
  int stride = gridDim.x * 256;
  for (; i < n4; i += stride){
    float4 v = ((const float4*)src)[i];
    ushort4 o;
    o.x = f2bf(v.x); o.y = f2bf(v.y); o.z = f2bf(v.z); o.w = f2bf(v.w);
    ((ushort4*)dst)[i] = o;
  }
}

// ---------------- embedding gather + h0 copy ----------------
// blocks 0..991: xemb[t*32+b] = emb[targets[b][t]]   (t<31)
// blocks 992..1055: copy encoder_hidden -> HBUF[0]
__global__ __launch_bounds__(128) void embed_k(const int* __restrict__ targets,
                                               const float* __restrict__ emb,
                                               const float* __restrict__ ench,
                                               float* __restrict__ xemb,
                                               float* __restrict__ h0){
  int blk = blockIdx.x;
  if (blk < 992){
    int t = blk >> 5, b = blk & 31;          // row m = t*32+b
    int tok = targets[b * 32 + t];
    const float4* src = (const float4*)(emb + (size_t)tok * 512);
    float4* dst = (float4*)(xemb + (size_t)blk * 512);
    dst[threadIdx.x] = src[threadIdx.x];     // 128 * float4 = 512
  } else {
    int i = (blk - 992) * 128 + threadIdx.x; // 64*128 = 8192 float4 = 32*1024
    ((float4*)h0)[i] = ((const float4*)ench)[i];
  }
}

// ---------------- generic f32 NT GEMM: C[m,n] = sum_k A[m,k]*B[n,k] + bias[n] ----------------
// 64x64 tile, 256 threads, 4x4 micro-tile, K-chunk 16, LDS transposed [k][m] stride 72.
__global__ __launch_bounds__(256) void gemm_f32_k(const float* __restrict__ A,
                                                  const float* __restrict__ B,
                                                  const float* __restrict__ bias,
                                                  float* __restrict__ C,
                                                  int M, int K, int lda, int ldb, int ldc){
  __shared__ float As[16 * 72];
  __shared__ float Bs[16 * 72];
  int tid = threadIdx.x;
  int m0 = blockIdx.y * 64, n0 = blockIdx.x * 64;
  int tx = tid & 15, ty = tid >> 4;
  int lrow = tid >> 2, lk = (tid & 3) * 4;
  const float* Ap = A + (size_t)(m0 + lrow) * lda + lk;
  const float* Bp = B + (size_t)(n0 + lrow) * ldb + lk;
  bool avalid = (m0 + lrow) < M;
  float acc[4][4] = {};
  for (int k0 = 0; k0 < K; k0 += 16){
    float4 av = avalid ? *(const float4*)(Ap + k0) : float4{0.f,0.f,0.f,0.f};
    float4 bv = *(const float4*)(Bp + k0);
    __syncthreads();
    As[(lk+0)*72 + lrow] = av.x; As[(lk+1)*72 + lrow] = av.y;
    As[(lk+2)*72 + lrow] = av.z; As[(lk+3)*72 + lrow] = av.w;
    Bs[(lk+0)*72 + lrow] = bv.x; Bs[(lk+1)*72 + lrow] = bv.y;
    Bs[(lk+2)*72 + lrow] = bv.z; Bs[(lk+3)*72 + lrow] = bv.w;
    __syncthreads();
#pragma unroll
    for (int kk = 0; kk < 16; ++kk){
      float4 a = *(const float4*)&As[kk*72 + ty*4];
      float4 b = *(const float4*)&Bs[kk*72 + tx*4];
      float avv[4] = {a.x, a.y, a.z, a.w};
      float bvv[4] = {b.x, b.y, b.z, b.w};
#pragma unroll
      for (int i = 0; i < 4; ++i)
#pragma unroll
        for (int j = 0; j < 4; ++j)
          acc[i][j] = fmaf(avv[i], bvv[j], acc[i][j]);
    }
  }
  float4 bb = *(const float4*)(bias + n0 + tx*4);
#pragma unroll
  for (int i = 0; i < 4; ++i){
    int row = m0 + ty*4 + i;
    if (row < M){
      float4 o;
      o.x = acc[i][0] + bb.x; o.y = acc[i][1] + bb.y;
      o.z = acc[i][2] + bb.z; o.w = acc[i][3] + bb.w;
      *(float4*)(C + (size_t)row * ldc + n0 + tx*4) = o;
    }
  }
}

// ---------------- step kernel 1: h_proj[b,k] = sum_d h[b,d] * W1[k, 1024+d] ----------------
__global__ __launch_bounds__(256) void hproj_k(const float* __restrict__ h,
                                               const float* __restrict__ W1,
                                               float* __restrict__ hp){
  int b = threadIdx.x & 31, kk = threadIdx.x >> 5;
  int k = blockIdx.x * 8 + kk;
  const float4* hr = (const float4*)(h + b * 1024);
  const float4* wr = (const float4*)(W1 + (size_t)k * 2048 + 1024);
  float acc = 0.f;
  for (int d = 0; d < 256; ++d){
    float4 a = hr[d], w = wr[d];
    acc = fmaf(a.x, w.x, fmaf(a.y, w.y, fmaf(a.z, w.z, fmaf(a.w, w.w, acc))));
  }
  hp[b * 1024 + k] = acc;
}

// ---------------- step kernel 2: attention scores + softmax + context (block = one b) ----------------
__global__ __launch_bounds__(256) void attn_k(const float* __restrict__ ep,
                                              const float* __restrict__ hp,
                                              const float* __restrict__ W2,
                                              const float* __restrict__ enc,
                                              float* __restrict__ ctx){
  __shared__ float hp_s[1024];
  __shared__ float w2_s[1024];
  __shared__ float e_s[50];
  int b = blockIdx.x;
  int tid = threadIdx.x, lane = tid & 63, w = tid >> 6;
  ((float4*)hp_s)[tid] = ((const float4*)(hp + b * 1024))[tid];
  ((float4*)w2_s)[tid] = ((const float4*)W2)[tid];
  __syncthreads();
  for (int s = w; s < 50; s += 4){
    const float* eprow = ep + (size_t)(b * 50 + s) * 1024;
    float v = 0.f;
#pragma unroll
    for (int kx = 0; kx < 16; ++kx){
      int k = lane + kx * 64;
      v += tanhf(eprow[k] + hp_s[k]) * w2_s[k];
    }
    for (int off = 32; off; off >>= 1) v += __shfl_xor(v, off);
    if (lane == 0) e_s[s] = v;
  }
  __syncthreads();
  float m = -1e30f;
  for (int s = 0; s < 50; ++s) m = fmaxf(m, e_s[s]);
  float sum = 0.f;
  for (int s = 0; s < 50; ++s) sum += expf(e_s[s] - m);
  float inv = 1.f / sum;
  float4 c = {0.f,0.f,0.f,0.f};
  const float4* encb = (const float4*)(enc + (size_t)b * 50 * 1024);
  for (int s = 0; s < 50; ++s){
    float a = expf(e_s[s] - m) * inv;
    float4 ev = encb[s * 256 + tid];
    c.x = fmaf(a, ev.x, c.x); c.y = fmaf(a, ev.y, c.y);
    c.z = fmaf(a, ev.z, c.z); c.w = fmaf(a, ev.w, c.w);
  }
  ((float4*)(ctx + b * 1024))[tid] = c;
}

// ---------------- step kernel 3: fused GRU (gi_c + gh dots + gates) ----------------
__global__ __launch_bounds__(256) void gru_k(const float* __restrict__ h,
                                             const float* __restrict__ ctx,
                                             const float* __restrict__ Wih,
                                             const float* __restrict__ Whh,
                                             const float* __restrict__ bhh,
                                             const float* __restrict__ gix_t,
                                             float* __restrict__ hnew){
  int b = threadIdx.x & 31, jj = threadIdx.x >> 5;
  int j = blockIdx.x * 8 + jj;
  const float4* hr = (const float4*)(h + b * 1024);
  const float4* cr = (const float4*)(ctx + b * 1024);
  const float4* wir = (const float4*)(Wih + (size_t)j * 1536 + 512);
  const float4* wiz = (const float4*)(Wih + (size_t)(1024 + j) * 1536 + 512);
  const float4* win = (const float4*)(Wih + (size_t)(2048 + j) * 1536 + 512);
  const float4* whr = (const float4*)(Whh + (size_t)j * 1024);
  const float4* whz = (const float4*)(Whh + (size_t)(1024 + j) * 1024);
  const float4* whn = (const float4*)(Whh + (size_t)(2048 + j) * 1024);
  float ar=0.f, az=0.f, an=0.f, br=0.f, bz=0.f, bn=0.f;
  for (int d = 0; d < 256; ++d){
    float4 cv = cr[d], hv = hr[d], w;
    w = wir[d]; ar += cv.x*w.x + cv.y*w.y + cv.z*w.z + cv.w*w.w;
    w = wiz[d]; az += cv.x*w.x + cv.y*w.y + cv.z*w.z + cv.w*w.w;
    w = win[d]; an += cv.x*w.x + cv.y*w.y + cv.z*w.z + cv.w*w.w;
    w = whr[d]; br += hv.x*w.x + hv.y*w.y + hv.z*w.z + hv.w*w.w;
    w = whz[d]; bz += hv.x*w.x + hv.y*w.y + hv.z*w.z + hv.w*w.w;
    w = whn[d]; bn += hv.x*w.x + hv.y*w.y + hv.z*w.z + hv.w*w.w;
  }
  float ir  = ar + gix_t[b * 3072 + j];
  float iz  = az + gix_t[b * 3072 + 1024 + j];
  float inn = an + gix_t[b * 3072 + 2048 + j];
  float hr_ = br + bhh[j];
  float hz_ = bz + bhh[1024 + j];
  float hn_ = bn + bhh[2048 + j];
  float r = 1.f / (1.f + expf(-(ir + hr_)));
  float z = 1.f / (1.f + expf(-(iz + hz_)));
  float n = tanhf(inn + r * hn_);
  float hv = h[b * 1024 + j];
  hnew[b * 1024 + j] = (1.f - z) * n + z * hv;
}

// ---------------- logits GEMM (bf16 MFMA): C[m,n] = sum_k A[m,k]*W[n,k] + b_out[n] ----------------
// M=992, N=32000, K=1024. Block 64m x 64n, 4 waves (wave w = n-subtile w*16).
// Writes to out[(b*31+t)*32000 + n] with m = t*32+b.
__global__ __launch_bounds__(256) void logits_k(const u16* __restrict__ Abf,
                                                const u16* __restrict__ Wbf,
                                                const float* __restrict__ bout,
                                                float* __restrict__ out){
  __shared__ u16 As[64 * 40];  // [m][k] rows padded to 40 shorts
  int tid = threadIdx.x, lane = tid & 63, w = tid >> 6;
  int n0 = blockIdx.x * 64, m0 = blockIdx.y * 64;
  int lr = tid >> 2, lk = (tid & 3) * 8;
  int r16 = lane & 15, kq = lane >> 4;
  bool avalid = (m0 + lr) < 992;
  const uint4* Ap = (const uint4*)(Abf + (size_t)(m0 + lr) * 1024 + lk);
  const uint4* Wp = (const uint4*)(Wbf + (size_t)(n0 + w * 16 + r16) * 1024 + kq * 8);
  f32x4 acc0 = {0.f,0.f,0.f,0.f}, acc1 = {0.f,0.f,0.f,0.f};
  f32x4 acc2 = {0.f,0.f,0.f,0.f}, acc3 = {0.f,0.f,0.f,0.f};
  for (int k0 = 0; k0 < 1024; k0 += 32){
    uint4 a4 = avalid ? Ap[k0 >> 3] : uint4{0,0,0,0};
    uint4 b4 = Wp[k0 >> 3];
    __syncthreads();
    *(uint4*)&As[lr * 40 + lk] = a4;
    __syncthreads();
    bf16x8 bfr = __builtin_bit_cast(bf16x8, b4);
    bf16x8 a0 = __builtin_bit_cast(bf16x8, *(const uint4*)&As[( 0 + r16) * 40 + kq * 8]);
    acc0 = __builtin_amdgcn_mfma_f32_16x16x32_bf16(a0, bfr, acc0, 0, 0, 0);
    bf16x8 a1 = __builtin_bit_cast(bf16x8, *(const uint4*)&As[(16 + r16) * 40 + kq * 8]);
    acc1 = __builtin_amdgcn_mfma_f32_16x16x32_bf16(a1, bfr, acc1, 0, 0, 0);
    bf16x8 a2 = __builtin_bit_cast(bf16x8, *(const uint4*)&As[(32 + r16) * 40 + kq * 8]);
    acc2 = __builtin_amdgcn_mfma_f32_16x16x32_bf16(a2, bfr, acc2, 0, 0, 0);
    bf16x8 a3 = __builtin_bit_cast(bf16x8, *(const uint4*)&As[(48 + r16) * 40 + kq * 8]);
    acc3 = __builtin_amdgcn_mfma_f32_16x16x32_bf16(a3, bfr, acc3, 0, 0, 0);
  }
  int n = n0 + w * 16 + r16;
  float bo = bout[n];
#define STORE_MS(MS, ACC)                                                        \
  {                                                                              \
    _Pragma("unroll")                                                            \
    for (int reg = 0; reg < 4; ++reg){                                           \
      int m = m0 + MS * 16 + kq * 4 + reg;                                       \
      if (m < 992){                                                              \
        int tt = m >> 5, bb = m & 31;                                            \
        out[(size_t)(bb * 31 + tt) * 32000 + n] = ACC[reg] + bo;                 \
      }                                                                          \
    }                                                                            \
  }
  STORE_MS(0, acc0) STORE_MS(1, acc1) STORE_MS(2, acc2) STORE_MS(3, acc3)
#undef STORE_MS
}

// ---------------- row-wise log_softmax over V=32000, in-place on d_out ----------------
__global__ __launch_bounds__(256) void lsm_k(float* __restrict__ out){
  __shared__ float red[4];
  __shared__ float red2[4];
  int row = blockIdx.x, tid = threadIdx.x, w = tid >> 6;
  float* p = out + (size_t)row * 32000;
  const float4* p4 = (const float4*)p;
  float m = -1e30f;
  for (int i = tid; i < 8000; i += 256){
    float4 v = p4[i];
    m = fmaxf(m, fmaxf(fmaxf(v.x, v.y), fmaxf(v.z, v.w)));
  }
  for (int off = 32; off; off >>= 1) m = fmaxf(m, __shfl_xor(m, off));
  if ((tid & 63) == 0) red[w] = m;
  __syncthreads();
  m = fmaxf(fmaxf(red[0], red[1]), fmaxf(red[2], red[3]));
  float s = 0.f;
  for (int i = tid; i < 8000; i += 256){
    float4 v = p4[i];
    s += expf(v.x - m) + expf(v.y - m) + expf(v.z - m) + expf(v.w - m);
  }
  for (int off = 32; off; off >>= 1) s += __shfl_xor(s, off);
  if ((tid & 63) == 0) red2[w] = s;
  __syncthreads();
  s = red2[0] + red2[1] + red2[2] + red2[3];
  float lse = m + logf(s);
  for (int i = tid; i < 8000; i += 256){
    float4 v = p4[i];
    v.x -= lse; v.y -= lse; v.z -= lse; v.w -= lse;
    ((float4*)p)[i] = v;
  }
}

extern "C" void kernel_launch(void* const* d_in, const int* in_sizes, int n_in,
                              void* d_out, int out_size, void* d_ws, size_t ws_size,
                              hipStream_t stream){
  const float* enc  = (const float*)d_in[0];   // (32,50,1024)
  const float* ench = (const float*)d_in[1];   // (1,32,1024)
  const int*   tgt  = (const int*)d_in[2];     // (32,32)
  const float* emb  = (const float*)d_in[3];   // (32000,512)
  const float* W1   = (const float*)d_in[4];   // (1024,2048)
  const float* b1   = (const float*)d_in[5];   // (1024)
  const float* W2   = (const float*)d_in[6];   // (1,1024)
  const float* Wih  = (const float*)d_in[7];   // (3072,1536)
  const float* bih  = (const float*)d_in[8];   // (3072)
  const float* Whh  = (const float*)d_in[9];   // (3072,1024)
  const float* bhh  = (const float*)d_in[10];  // (3072)
  const float* Wout = (const float*)d_in[11];  // (32000,1024)
  const float* bout = (const float*)d_in[12];  // (32000)
  float* out = (float*)d_out;

  char* ws = (char*)d_ws;
  size_t off = 0;
  auto alloc = [&](size_t bytes)->char*{
    char* p = ws + off;
    off += (bytes + 255) & ~(size_t)255;
    return p;
  };
  float* EP   = (float*)alloc((size_t)1600 * 1024 * 4);  // enc_proj (+b1)
  float* GIX  = (float*)alloc((size_t)992 * 3072 * 4);   // x-part of gi (+b_ih)
  float* XEMB = (float*)alloc((size_t)992 * 512 * 4);    // gathered embeddings
  float* HBUF = (float*)alloc((size_t)32 * 32 * 1024 * 4); // h states: slot 0 = h0
  float* HP   = (float*)alloc((size_t)32 * 1024 * 4);    // h_proj
  float* CTX  = (float*)alloc((size_t)32 * 1024 * 4);    // context
  u16*   WBF  = (u16*)alloc((size_t)32000 * 1024 * 2);   // W_out bf16
  u16*   ABF  = (u16*)alloc((size_t)992 * 1024 * 2);     // H_all bf16
  (void)ws_size; (void)in_sizes; (void)n_in; (void)out_size;

  // Phase A (parallel pre-work)
  conv_bf16_k<<<2048, 256, 0, stream>>>(Wout, WBF, 32000 * 1024 / 4);
  embed_k<<<1056, 128, 0, stream>>>(tgt, emb, ench, XEMB, HBUF);
  // enc_proj: M=1600,N=1024,K=1024  A=enc lda=1024, B=W1 ldb=2048 (cols 0..1023), bias=b1
  gemm_f32_k<<<dim3(16, 25), 256, 0, stream>>>(enc, W1, b1, EP, 1600, 1024, 1024, 2048, 1024);
  // gi_x: M=992,N=3072,K=512  A=XEMB lda=512, B=W_ih ldb=1536 (cols 0..511), bias=b_ih
  gemm_f32_k<<<dim3(48, 16), 256, 0, stream>>>(XEMB, Wih, bih, GIX, 992, 512, 512, 1536, 3072);

  // Phase B (serial recurrence)
  for (int t = 0; t < 31; ++t){
    const float* h = HBUF + (size_t)t * 32768;
    hproj_k<<<128, 256, 0, stream>>>(h, W1, HP);
    attn_k<<<32, 256, 0, stream>>>(EP, HP, W2, enc, CTX);
    gru_k<<<128, 256, 0, stream>>>(h, CTX, Wih, Whh, bhh,
                                   GIX + (size_t)t * 32 * 3072,
                                   HBUF + (size_t)(t + 1) * 32768);
  }

  // Phase C (deferred output projection + log_softmax)
  conv_bf16_k<<<1024, 256, 0, stream>>>(HBUF + 32768, ABF, 992 * 1024 / 4);
  logits_k<<<dim3(500, 16), 256, 0, stream>>>(ABF, WBF, bout, out);
  lsm_k<<<992, 256, 0, stream>>>(out);
}